// Round 1
// baseline (534.422 us; speedup 1.0000x reference)
//
#include <hip/hip_runtime.h>
#include <hip/hip_bf16.h>

// EdgeFFN: out[e] = relu(concat(x[src[e]], x[dst[e]]) @ W1 + b1) @ W2 + b2
// E=640000, IN=128, CAT=256, HID=256, OUT=64

#define N_EDGES_C 640000
#define N_NODES_C 100000
#define IN_DIM_C  128
#define CAT_DIM_C 256
#define HIDDEN_C  256
#define OUT_DIM_C 64
#define BM        64    // edges per block
#define LDA       264   // padded LDS row (256 + 8 bf16 -> +16B) to break bank conflicts

typedef __attribute__((ext_vector_type(8))) short bf16x8;
typedef __attribute__((ext_vector_type(4))) float f32x4;

__device__ __forceinline__ ushort f2bs(float f) {
  union { __hip_bfloat16 h; ushort u; } c;
  c.h = __float2bfloat16(f);
  return c.u;
}

// ---- prep: cast node features f32 -> bf16 (vectorized 8/thread) ----
__global__ __launch_bounds__(256) void cast_x_kernel(const float* __restrict__ x,
                                                     ushort* __restrict__ xb) {
  const int i = blockIdx.x * 256 + threadIdx.x;   // 1.6M threads * 8 elems = 12.8M
  const float4 v0 = reinterpret_cast<const float4*>(x)[2 * i];
  const float4 v1 = reinterpret_cast<const float4*>(x)[2 * i + 1];
  uint4 o;
  o.x = (unsigned)f2bs(v0.x) | ((unsigned)f2bs(v0.y) << 16);
  o.y = (unsigned)f2bs(v0.z) | ((unsigned)f2bs(v0.w) << 16);
  o.z = (unsigned)f2bs(v1.x) | ((unsigned)f2bs(v1.y) << 16);
  o.w = (unsigned)f2bs(v1.z) | ((unsigned)f2bs(v1.w) << 16);
  reinterpret_cast<uint4*>(xb)[i] = o;
}

// ---- prep: transpose + cast weights so MFMA B-fragments are contiguous in k ----
// W1t[n][k] = W1[k][n]  (256x256), W2t[o][k] = W2[k][o]  (64x256)
__global__ __launch_bounds__(256) void prep_w_kernel(const float* __restrict__ W1,
                                                     const float* __restrict__ W2,
                                                     ushort* __restrict__ W1t,
                                                     ushort* __restrict__ W2t) {
  const int i = blockIdx.x * 256 + threadIdx.x;   // 320 blocks * 256 = 81920
  if (i < HIDDEN_C * CAT_DIM_C) {
    const int n = i >> 8, k = i & 255;
    W1t[i] = f2bs(W1[k * HIDDEN_C + n]);
  } else {
    const int j = i - HIDDEN_C * CAT_DIM_C;
    const int o = j >> 8, k = j & 255;
    W2t[j] = f2bs(W2[k * OUT_DIM_C + o]);
  }
}

// ---- main fused kernel ----
// block = 256 threads (4 waves), BM=64 edges. Wave w: GEMM1 cols [w*64,w*64+64),
// GEMM2 rows [w*16,w*16+16). 16x16x32 bf16 MFMA.
// A-frag: lane reads A[row = l&15][k = ks*32 + (l>>4)*8 .. +8]  (contiguous 16B)
// B-frag: lane reads Bt[col = l&15-based][same k range]          (contiguous 16B)
// C/D  : row = (l>>4)*4 + reg, col = l&15   [m89-verified]
template <int USE_XB>
__global__ __launch_bounds__(256) void edge_ffn_kernel(
    const ushort* __restrict__ xb, const float* __restrict__ xf,
    const int* __restrict__ ei,
    const ushort* __restrict__ W1t, const float* __restrict__ b1,
    const ushort* __restrict__ W2t, const float* __restrict__ b2,
    float* __restrict__ out) {
  __shared__ ushort A[BM * LDA];   // 33,792 B; reused for H after GEMM1

  const int tid  = threadIdx.x;
  const int lane = tid & 63;
  const int w    = tid >> 6;
  const int e0   = blockIdx.x * BM;
  const int l15  = lane & 15;
  const int lg   = lane >> 4;

  // ---------- stage gathered [src|dst] bf16 rows into LDS ----------
  {
    const int li  = tid & 15;        // 16 lanes cover one 128-elem half-row
    const int hr0 = tid >> 4;        // 0..15
#pragma unroll
    for (int it = 0; it < 8; ++it) {
      const int hr    = hr0 + it * 16;        // 0..127 half-rows
      const int edge  = hr >> 1;
      const int which = hr & 1;               // 0 = src half, 1 = dst half
      const int node  = ei[which * N_EDGES_C + e0 + edge];
      ushort* dst = &A[edge * LDA + which * IN_DIM_C + li * 8];
      if (USE_XB) {
        *reinterpret_cast<uint4*>(dst) =
            *reinterpret_cast<const uint4*>(xb + node * IN_DIM_C + li * 8);
      } else {
        const float4* row = reinterpret_cast<const float4*>(xf + node * IN_DIM_C);
        const float4 v0 = row[li * 2];
        const float4 v1 = row[li * 2 + 1];
        uint4 o;
        o.x = (unsigned)f2bs(v0.x) | ((unsigned)f2bs(v0.y) << 16);
        o.y = (unsigned)f2bs(v0.z) | ((unsigned)f2bs(v0.w) << 16);
        o.z = (unsigned)f2bs(v1.x) | ((unsigned)f2bs(v1.y) << 16);
        o.w = (unsigned)f2bs(v1.z) | ((unsigned)f2bs(v1.w) << 16);
        *reinterpret_cast<uint4*>(dst) = o;
      }
    }
  }
  __syncthreads();

  // ---------- GEMM1: h[64 x 256] = A[64 x 256] @ W1 ----------
  f32x4 acc[4][4];
#pragma unroll
  for (int m = 0; m < 4; ++m)
#pragma unroll
    for (int n = 0; n < 4; ++n) acc[m][n] = (f32x4){0.f, 0.f, 0.f, 0.f};

#pragma unroll
  for (int ks = 0; ks < 8; ++ks) {
    const int kb = ks * 32 + lg * 8;
    bf16x8 a[4], b[4];
#pragma unroll
    for (int m = 0; m < 4; ++m)
      a[m] = *reinterpret_cast<const bf16x8*>(&A[(m * 16 + l15) * LDA + kb]);
#pragma unroll
    for (int n = 0; n < 4; ++n) {
      const int col = w * 64 + n * 16 + l15;
      b[n] = *reinterpret_cast<const bf16x8*>(W1t + col * CAT_DIM_C + kb);
    }
#pragma unroll
    for (int m = 0; m < 4; ++m)
#pragma unroll
      for (int n = 0; n < 4; ++n)
        acc[m][n] = __builtin_amdgcn_mfma_f32_16x16x32_bf16(a[m], b[n], acc[m][n], 0, 0, 0);
  }

  // ---------- bias + relu, h -> bf16 back into LDS (reuse A) ----------
  float b1v[4];
#pragma unroll
  for (int n = 0; n < 4; ++n) b1v[n] = b1[w * 64 + n * 16 + l15];

  __syncthreads();   // all waves done reading A before overwrite
#pragma unroll
  for (int m = 0; m < 4; ++m)
#pragma unroll
    for (int n = 0; n < 4; ++n)
#pragma unroll
      for (int i = 0; i < 4; ++i) {
        float v = acc[m][n][i] + b1v[n];
        v = v > 0.f ? v : 0.f;
        const int row = m * 16 + lg * 4 + i;
        const int col = w * 64 + n * 16 + l15;
        A[row * LDA + col] = f2bs(v);
      }
  __syncthreads();   // H visible to all waves

  // ---------- GEMM2: out[64 x 64] = H[64 x 256] @ W2 ----------
  f32x4 acc2[4];
#pragma unroll
  for (int n = 0; n < 4; ++n) acc2[n] = (f32x4){0.f, 0.f, 0.f, 0.f};

#pragma unroll
  for (int ks = 0; ks < 8; ++ks) {
    const int kb = ks * 32 + lg * 8;
    const bf16x8 a2 = *reinterpret_cast<const bf16x8*>(&A[(w * 16 + l15) * LDA + kb]);
#pragma unroll
    for (int n = 0; n < 4; ++n) {
      const bf16x8 bb =
          *reinterpret_cast<const bf16x8*>(W2t + (n * 16 + l15) * HIDDEN_C + kb);
      acc2[n] = __builtin_amdgcn_mfma_f32_16x16x32_bf16(a2, bb, acc2[n], 0, 0, 0);
    }
  }

  // ---------- epilogue: + b2, store f32 ----------
  float b2v[4];
#pragma unroll
  for (int n = 0; n < 4; ++n) b2v[n] = b2[n * 16 + l15];
#pragma unroll
  for (int n = 0; n < 4; ++n)
#pragma unroll
    for (int i = 0; i < 4; ++i) {
      const int row = e0 + w * 16 + lg * 4 + i;
      out[row * OUT_DIM_C + n * 16 + l15] = acc2[n][i] + b2v[n];
    }
}

extern "C" void kernel_launch(void* const* d_in, const int* in_sizes, int n_in,
                              void* d_out, int out_size, void* d_ws, size_t ws_size,
                              hipStream_t stream) {
  const float* x  = (const float*)d_in[0];
  const int*   ei = (const int*)d_in[1];
  const float* W1 = (const float*)d_in[2];
  const float* b1 = (const float*)d_in[3];
  const float* W2 = (const float*)d_in[4];
  const float* b2 = (const float*)d_in[5];
  float* out = (float*)d_out;

  const size_t xb_elems  = (size_t)N_NODES_C * IN_DIM_C;   // 12.8M bf16
  const size_t w1t_elems = HIDDEN_C * CAT_DIM_C;           // 65536
  const size_t w2t_elems = OUT_DIM_C * HIDDEN_C;           // 16384
  const size_t need_full = (xb_elems + w1t_elems + w2t_elems) * sizeof(ushort);

  ushort* base = (ushort*)d_ws;
  if (ws_size >= need_full) {
    ushort* xbp = base;
    ushort* W1t = xbp + xb_elems;
    ushort* W2t = W1t + w1t_elems;
    cast_x_kernel<<<(N_NODES_C * IN_DIM_C) / (256 * 8), 256, 0, stream>>>(x, xbp);
    prep_w_kernel<<<(HIDDEN_C * CAT_DIM_C + OUT_DIM_C * HIDDEN_C) / 256, 256, 0, stream>>>(
        W1, W2, W1t, W2t);
    edge_ffn_kernel<1><<<N_EDGES_C / BM, 256, 0, stream>>>(xbp, x, ei, W1t, b1, W2t, b2, out);
  } else {
    // ws too small for cached bf16 x: convert during gather instead
    ushort* W1t = base;
    ushort* W2t = W1t + w1t_elems;
    prep_w_kernel<<<(HIDDEN_C * CAT_DIM_C + OUT_DIM_C * HIDDEN_C) / 256, 256, 0, stream>>>(
        W1, W2, W1t, W2t);
    edge_ffn_kernel<0><<<N_EDGES_C / BM, 256, 0, stream>>>(nullptr, x, ei, W1t, b1, W2t, b2, out);
  }
}